// Round 2
// baseline (1545.316 us; speedup 1.0000x reference)
//
#include <hip/hip_runtime.h>
#include <stdint.h>

#define DI __device__ __forceinline__

DI float lrelu(float x){ return x >= 0.0f ? x : 0.01f*x; }

// ---------------- threefry2x32, JAX key(42) => (0, 42) ----------------
DI uint32_t rotl32(uint32_t x, int d){ return (x << d) | (x >> (32 - d)); }

DI void threefry_0_42(uint32_t& x0, uint32_t& x1){
  const uint32_t ks0 = 0u, ks1 = 42u, ks2 = 0x1BD11BF0u; // 0 ^ 42 ^ 0x1BD11BDA
  x0 += ks0; x1 += ks1;
  #define TFR(d) { x0 += x1; x1 = rotl32(x1,(d)); x1 ^= x0; }
  TFR(13) TFR(15) TFR(26) TFR(6)  x0 += ks1; x1 += ks2 + 1u;
  TFR(17) TFR(29) TFR(16) TFR(24) x0 += ks2; x1 += ks0 + 2u;
  TFR(13) TFR(15) TFR(26) TFR(6)  x0 += ks0; x1 += ks1 + 3u;
  TFR(17) TFR(29) TFR(16) TFR(24) x0 += ks1; x1 += ks2 + 4u;
  TFR(13) TFR(15) TFR(26) TFR(6)  x0 += ks2; x1 += ks0 + 5u;
  #undef TFR
}

// XLA/Giles single-precision erfinv (same coefficients as chlo erf_inv f32)
DI float erfinv_f32(float x){
  float w = -log1pf(-x*x);
  float p;
  if (w < 5.0f){
    w = w - 2.5f;
    p = 2.81022636e-08f;
    p = fmaf(p, w, 3.43273939e-07f);
    p = fmaf(p, w, -3.5233877e-06f);
    p = fmaf(p, w, -4.39150654e-06f);
    p = fmaf(p, w, 0.00021858087f);
    p = fmaf(p, w, -0.00125372503f);
    p = fmaf(p, w, -0.00417768164f);
    p = fmaf(p, w, 0.246640727f);
    p = fmaf(p, w, 1.50140941f);
  } else {
    w = sqrtf(w) - 3.0f;
    p = -0.000200214257f;
    p = fmaf(p, w, 0.000100950558f);
    p = fmaf(p, w, 0.00134934322f);
    p = fmaf(p, w, -0.00367342844f);
    p = fmaf(p, w, 0.00573950773f);
    p = fmaf(p, w, -0.0076224613f);
    p = fmaf(p, w, 0.00943887047f);
    p = fmaf(p, w, 1.00167406f);
    p = fmaf(p, w, 2.83297682f);
  }
  return p * x;
}

// out offsets (floats)
#define OUT_D_OFF   0
#define OUT_MU_OFF  12288000
#define OUT_LV_OFF  (12288000 + 3840)
#define OUT_Z_OFF   (12288000 + 7680)

// =====================================================================
// enc1: conv(x,w1,SAME 3x3, 6->8) + lrelu + maxpool 2x2  -> p1[32,8,250,64]
__global__ __launch_bounds__(256) void k_enc1(const float* __restrict__ x,
                                              const float* __restrict__ w1,
                                              float* __restrict__ p1){
  __shared__ float wl[432];
  int tid = threadIdx.x;
  for (int i = tid; i < 432; i += 256) wl[i] = w1[i];
  __syncthreads();
  int t = blockIdx.x*256 + tid;
  int pw = t & 63; int u = t >> 6; int ph = u % 250; int b = u / 250;
  float acc[2][2][8];
  #pragma unroll
  for (int a=0;a<2;a++)
    #pragma unroll
    for (int d=0;d<2;d++)
      #pragma unroll
      for (int o=0;o<8;o++) acc[a][d][o] = 0.0f;
  int r0 = 2*ph - 1, c0 = 2*pw - 1;
  for (int c = 0; c < 6; ++c){
    float win[4][4];
    #pragma unroll
    for (int i=0;i<4;i++){
      int r = r0 + i; bool rok = ((unsigned)r < 500u);
      #pragma unroll
      for (int j=0;j<4;j++){
        int cc = c0 + j;
        win[i][j] = (rok && (unsigned)cc < 128u) ? x[((b*6+c)*500+r)*128+cc] : 0.0f;
      }
    }
    #pragma unroll
    for (int kh=0;kh<3;kh++)
      #pragma unroll
      for (int kw=0;kw<3;kw++){
        float wv[8];
        #pragma unroll
        for (int o=0;o<8;o++) wv[o] = wl[((o*6+c)*3+kh)*3+kw];
        #pragma unroll
        for (int dy=0;dy<2;dy++)
          #pragma unroll
          for (int dx=0;dx<2;dx++){
            float v = win[dy+kh][dx+kw];
            #pragma unroll
            for (int o=0;o<8;o++) acc[dy][dx][o] = fmaf(v, wv[o], acc[dy][dx][o]);
          }
      }
  }
  #pragma unroll
  for (int o=0;o<8;o++){
    float m = fmaxf(fmaxf(acc[0][0][o], acc[0][1][o]), fmaxf(acc[1][0][o], acc[1][1][o]));
    p1[((b*8+o)*250+ph)*64+pw] = lrelu(m); // lrelu monotonic => pool-then-lrelu
  }
}

// =====================================================================
// enc2: conv(p1,w2,SAME 3x3, 8->16)+lrelu+maxpool(5,2) -> p2[32,16,50,32]
__global__ __launch_bounds__(256) void k_enc2(const float* __restrict__ in,
                                              const float* __restrict__ w2,
                                              float* __restrict__ p2){
  __shared__ float wl[1152];
  int tid = threadIdx.x;
  for (int i = tid; i < 1152; i += 256) wl[i] = w2[i];
  __syncthreads();
  int t = blockIdx.x*256 + tid;
  int dx = t & 1; int u = t >> 1;
  int pw = u & 31; u >>= 5; int ph = u % 50; int b = u / 50;
  int cw = 2*pw + dx;
  float acc[5][16];
  #pragma unroll
  for (int dy=0;dy<5;dy++)
    #pragma unroll
    for (int o=0;o<16;o++) acc[dy][o] = 0.0f;
  int r0 = 5*ph - 1, c0 = cw - 1;
  for (int c = 0; c < 8; ++c){
    float win[7][3];
    #pragma unroll
    for (int i=0;i<7;i++){
      int r = r0 + i; bool rok = ((unsigned)r < 250u);
      #pragma unroll
      for (int j=0;j<3;j++){
        int cc = c0 + j;
        win[i][j] = (rok && (unsigned)cc < 64u) ? in[((b*8+c)*250+r)*64+cc] : 0.0f;
      }
    }
    #pragma unroll
    for (int kh=0;kh<3;kh++)
      #pragma unroll
      for (int kw=0;kw<3;kw++){
        float wv[16];
        #pragma unroll
        for (int o=0;o<16;o++) wv[o] = wl[((o*8+c)*3+kh)*3+kw];
        #pragma unroll
        for (int dy=0;dy<5;dy++){
          float v = win[dy+kh][kw];
          #pragma unroll
          for (int o=0;o<16;o++) acc[dy][o] = fmaf(v, wv[o], acc[dy][o]);
        }
      }
  }
  #pragma unroll
  for (int o=0;o<16;o++){
    float m = acc[0][o];
    #pragma unroll
    for (int dy=1;dy<5;dy++) m = fmaxf(m, acc[dy][o]);
    m = fmaxf(m, __shfl_xor(m, 1));
    if (dx == 0) p2[((b*16+o)*50+ph)*32+pw] = lrelu(m);
  }
}

// =====================================================================
// conv3: conv(p2,w3,SAME 3x3, 16->32)+lrelu -> h3[32,32,50,32]
__global__ __launch_bounds__(256) void k_conv3(const float* __restrict__ in,
                                               const float* __restrict__ w3,
                                               float* __restrict__ outp){
  __shared__ float wl[4608];
  int tid = threadIdx.x;
  for (int i = tid; i < 4608; i += 256) wl[i] = w3[i];
  __syncthreads();
  int t = blockIdx.x*256 + tid;
  int w = t & 31; int u = t >> 5; int h = u % 50; u /= 50; int oh = u & 1; int b = u >> 1;
  float acc[16];
  #pragma unroll
  for (int o=0;o<16;o++) acc[o] = 0.0f;
  int r0 = h - 1, c0 = w - 1;
  for (int c = 0; c < 16; ++c){
    float win[3][3];
    #pragma unroll
    for (int i=0;i<3;i++){
      int r = r0 + i; bool rok = ((unsigned)r < 50u);
      #pragma unroll
      for (int j=0;j<3;j++){
        int cc = c0 + j;
        win[i][j] = (rok && (unsigned)cc < 32u) ? in[((b*16+c)*50+r)*32+cc] : 0.0f;
      }
    }
    #pragma unroll
    for (int kh=0;kh<3;kh++)
      #pragma unroll
      for (int kw=0;kw<3;kw++){
        float v = win[kh][kw];
        #pragma unroll
        for (int o=0;o<16;o++)
          acc[o] = fmaf(v, wl[(((oh*16+o)*16+c)*3+kh)*3+kw], acc[o]);
      }
  }
  #pragma unroll
  for (int o=0;o<16;o++)
    outp[((b*32 + oh*16 + o)*50 + h)*32 + w] = lrelu(acc[o]);
}

// =====================================================================
// pool3: maxpool(5,2) on h3 -> p3[32,32,10,16]
__global__ __launch_bounds__(256) void k_pool3(const float* __restrict__ in,
                                               float* __restrict__ outp){
  int t = blockIdx.x*256 + threadIdx.x;
  int pw = t & 15; int u = t >> 4; int ph = u % 10; u /= 10; int o = u & 31; int b = u >> 5;
  float m = -INFINITY;
  #pragma unroll
  for (int dh=0;dh<5;dh++)
    #pragma unroll
    for (int dw=0;dw<2;dw++)
      m = fmaxf(m, in[((b*32+o)*50 + 5*ph+dh)*32 + 2*pw+dw]);
  outp[((b*32+o)*10+ph)*16+pw] = m;
}

// =====================================================================
// latent: mu/logvar conv (1,5) VALID 32->1, reparameterize with threefry eps
// eps uses JAX *partitionable* threefry (default since jax 0.4.36):
//   per element t: (y0,y1) = threefry(key=(0,42), counter=(hi,lo)=(0,t));
//   bits = y0 ^ y1; then bits>>9 | 1.0f-bits, u = max(lo, f*2+lo), sqrt2*erfinv.
__global__ __launch_bounds__(256) void k_latent(const float* __restrict__ p3,
                                                const float* __restrict__ wmu,
                                                const float* __restrict__ wlv,
                                                float* __restrict__ outp){
  int t = blockIdx.x*256 + threadIdx.x; // 3840 total
  int w = t % 12; int h = (t/12) % 10; int b = t/120;
  float mu = 0.0f, lv = 0.0f;
  for (int c = 0; c < 32; ++c){
    const float* row = p3 + ((b*32+c)*10+h)*16 + w;
    #pragma unroll
    for (int kw=0;kw<5;kw++){
      float v = row[kw];
      mu = fmaf(v, wmu[c*5+kw], mu);
      lv = fmaf(v, wlv[c*5+kw], lv);
    }
  }
  // partitionable threefry: counter = uint64 t -> (hi=0, lo=t); bits = y0^y1
  uint32_t x0 = 0u, x1 = (uint32_t)t;
  threefry_0_42(x0, x1);
  uint32_t bits = x0 ^ x1;
  float f = __uint_as_float((bits >> 9) | 0x3f800000u) - 1.0f; // [0,1)
  const float lo = -0.99999994f; // nextafter(-1,0) in f32; (1-lo) rounds to 2.0f
  float uu = fmaxf(lo, f * 2.0f + lo);
  float eps = 1.41421356f * erfinv_f32(uu);
  float z = mu + eps * expf(0.5f * lv);
  outp[OUT_MU_OFF + t] = mu;
  outp[OUT_LV_OFF + t] = lv;
  outp[OUT_Z_OFF  + t] = z;
}

// =====================================================================
// dec0: convT(z, wu0[32,1,1,5], stride 1, VALID) + lrelu -> d0[32,32,10,16]
__global__ __launch_bounds__(256) void k_dec0(const float* __restrict__ outp, // d_out base (z lives there)
                                              const float* __restrict__ wu0,
                                              float* __restrict__ d0){
  int t = blockIdx.x*256 + threadIdx.x;
  int w = t & 15; int u = t >> 4; int h = u % 10; u /= 10; int o = u & 31; int b = u >> 5;
  const float* z = outp + OUT_Z_OFF;
  float a = 0.0f;
  #pragma unroll
  for (int kw=0;kw<5;kw++){
    int ww = w + kw - 4;
    if ((unsigned)ww < 12u) a = fmaf(z[b*120 + h*12 + ww], wu0[o*5+kw], a);
  }
  d0[((b*32+o)*10+h)*16+w] = lrelu(a);
}

// =====================================================================
// dec1: convT(d0, wu1[32,32,5,2], strides (5,2)) + lrelu -> d1[32,32,50,32]
// kernel==stride: out[o,5i+r,2j+s] = sum_c d0[c,i,j]*wu1[o,c,4-r,1-s]
__global__ __launch_bounds__(256) void k_dec1(const float* __restrict__ d0,
                                              const float* __restrict__ wu1,
                                              float* __restrict__ d1){
  int t = blockIdx.x*256 + threadIdx.x;
  int wo = t & 31; int u = t >> 5; int ho = u % 50; u /= 50; int o = u & 31; int b = u >> 5;
  int i = ho / 5, r = ho - 5*i, jj = wo >> 1, s = wo & 1;
  const float* ip = d0 + b*5120 + i*16 + jj;             // + c*160
  const float* wp = wu1 + (o*32*5 + (4-r))*2 + (1-s);    // + c*10
  float a = 0.0f;
  #pragma unroll
  for (int c=0;c<32;c++) a = fmaf(ip[c*160], wp[c*10], a);
  d1[((b*32+o)*50+ho)*32+wo] = lrelu(a);
}

// =====================================================================
// c4: conv(d1, w4[16,32,3,3], SAME)+lrelu -> d2[32,16,50,32]
__global__ __launch_bounds__(256) void k_c4(const float* __restrict__ in,
                                            const float* __restrict__ w4,
                                            float* __restrict__ outp){
  __shared__ float wl[4608];
  int tid = threadIdx.x;
  for (int i = tid; i < 4608; i += 256) wl[i] = w4[i];
  __syncthreads();
  int t = blockIdx.x*256 + tid;
  int w = t & 31; int u = t >> 5; int h = u % 50; u /= 50; int oh = u & 1; int b = u >> 1;
  float acc[8];
  #pragma unroll
  for (int o=0;o<8;o++) acc[o] = 0.0f;
  int r0 = h - 1, c0 = w - 1;
  for (int c = 0; c < 32; ++c){
    float win[3][3];
    #pragma unroll
    for (int i=0;i<3;i++){
      int r = r0 + i; bool rok = ((unsigned)r < 50u);
      #pragma unroll
      for (int j=0;j<3;j++){
        int cc = c0 + j;
        win[i][j] = (rok && (unsigned)cc < 32u) ? in[((b*32+c)*50+r)*32+cc] : 0.0f;
      }
    }
    #pragma unroll
    for (int kh=0;kh<3;kh++)
      #pragma unroll
      for (int kw=0;kw<3;kw++){
        float v = win[kh][kw];
        #pragma unroll
        for (int o=0;o<8;o++)
          acc[o] = fmaf(v, wl[(((oh*8+o)*32+c)*3+kh)*3+kw], acc[o]);
      }
  }
  #pragma unroll
  for (int o=0;o<8;o++)
    outp[((b*16 + oh*8 + o)*50 + h)*32 + w] = lrelu(acc[o]);
}

// =====================================================================
// u2: convT(d2, wu2[16,16,5,2], strides (5,2)) + lrelu -> d3[32,16,250,64]
__global__ __launch_bounds__(256) void k_u2(const float* __restrict__ d2,
                                            const float* __restrict__ wu2,
                                            float* __restrict__ d3){
  int t = blockIdx.x*256 + threadIdx.x;
  int w = t & 63; int u = t >> 6; int h = u % 250; u /= 250; int o = u & 15; int b = u >> 4;
  int i = h / 5, r = h - 5*i, jj = w >> 1, s = w & 1;
  const float* ip = d2 + b*25600 + i*32 + jj;            // + c*1600
  const float* wp = wu2 + (o*16*5 + (4-r))*2 + (1-s);    // + c*10
  float a = 0.0f;
  #pragma unroll
  for (int c=0;c<16;c++) a = fmaf(ip[c*1600], wp[c*10], a);
  d3[((b*16+o)*250+h)*64+w] = lrelu(a);
}

// =====================================================================
// c5: conv(d3, w5[8,16,3,3], SAME)+lrelu -> d4[32,8,250,64]
__global__ __launch_bounds__(256) void k_c5(const float* __restrict__ in,
                                            const float* __restrict__ w5,
                                            float* __restrict__ outp){
  __shared__ float wl[1152];
  int tid = threadIdx.x;
  for (int i = tid; i < 1152; i += 256) wl[i] = w5[i];
  __syncthreads();
  int t = blockIdx.x*256 + tid;
  int w = t & 63; int u = t >> 6; int h = u % 250; int b = u / 250;
  float acc[8];
  #pragma unroll
  for (int o=0;o<8;o++) acc[o] = 0.0f;
  int r0 = h - 1, c0 = w - 1;
  for (int c = 0; c < 16; ++c){
    float win[3][3];
    #pragma unroll
    for (int i=0;i<3;i++){
      int r = r0 + i; bool rok = ((unsigned)r < 250u);
      #pragma unroll
      for (int j=0;j<3;j++){
        int cc = c0 + j;
        win[i][j] = (rok && (unsigned)cc < 64u) ? in[((b*16+c)*250+r)*64+cc] : 0.0f;
      }
    }
    #pragma unroll
    for (int kh=0;kh<3;kh++)
      #pragma unroll
      for (int kw=0;kw<3;kw++){
        float v = win[kh][kw];
        #pragma unroll
        for (int o=0;o<8;o++)
          acc[o] = fmaf(v, wl[((o*16+c)*3+kh)*3+kw], acc[o]);
      }
  }
  #pragma unroll
  for (int o=0;o<8;o++)
    outp[((b*8+o)*250+h)*64+w] = lrelu(acc[o]);
}

// =====================================================================
// u3: convT(d4, wu3[8,8,2,2], strides (2,2)) + lrelu -> d5[32,8,500,128]
__global__ __launch_bounds__(256) void k_u3(const float* __restrict__ d4,
                                            const float* __restrict__ wu3,
                                            float* __restrict__ d5){
  int t = blockIdx.x*256 + threadIdx.x;
  int w = t & 127; int u = t >> 7; int h = u % 500; u /= 500; int o = u & 7; int b = u >> 3;
  int i = h >> 1, r = h & 1, jj = w >> 1, s = w & 1;
  const float* ip = d4 + b*128000 + i*64 + jj;           // + c*16000
  const float* wp = wu3 + (o*8*2 + (1-r))*2 + (1-s);     // + c*4
  float a = 0.0f;
  #pragma unroll
  for (int c=0;c<8;c++) a = fmaf(ip[c*16000], wp[c*4], a);
  d5[((b*8+o)*500+h)*128+w] = lrelu(a);
}

// =====================================================================
// c6: conv(d5, w6[6,8,3,3], SAME)+lrelu -> d_out[32,6,500,128]
__global__ __launch_bounds__(256) void k_c6(const float* __restrict__ in,
                                            const float* __restrict__ w6,
                                            float* __restrict__ outp){
  __shared__ float wl[432];
  int tid = threadIdx.x;
  for (int i = tid; i < 432; i += 256) wl[i] = w6[i];
  __syncthreads();
  int t = blockIdx.x*256 + tid;
  int w = t & 127; int u = t >> 7; int h = u % 500; int b = u / 500;
  float acc[6];
  #pragma unroll
  for (int o=0;o<6;o++) acc[o] = 0.0f;
  int r0 = h - 1, c0 = w - 1;
  for (int c = 0; c < 8; ++c){
    float win[3][3];
    #pragma unroll
    for (int i=0;i<3;i++){
      int r = r0 + i; bool rok = ((unsigned)r < 500u);
      #pragma unroll
      for (int j=0;j<3;j++){
        int cc = c0 + j;
        win[i][j] = (rok && (unsigned)cc < 128u) ? in[((b*8+c)*500+r)*128+cc] : 0.0f;
      }
    }
    #pragma unroll
    for (int kh=0;kh<3;kh++)
      #pragma unroll
      for (int kw=0;kw<3;kw++){
        float v = win[kh][kw];
        #pragma unroll
        for (int o=0;o<6;o++)
          acc[o] = fmaf(v, wl[((o*8+c)*3+kh)*3+kw], acc[o]);
      }
  }
  #pragma unroll
  for (int o=0;o<6;o++)
    outp[((b*6+o)*500+h)*128+w] = lrelu(acc[o]);
}

// =====================================================================
extern "C" void kernel_launch(void* const* d_in, const int* in_sizes, int n_in,
                              void* d_out, int out_size, void* d_ws, size_t ws_size,
                              hipStream_t stream){
  const float* x   = (const float*)d_in[0];
  const float* w1  = (const float*)d_in[1];
  const float* w2  = (const float*)d_in[2];
  const float* w3  = (const float*)d_in[3];
  const float* wmu = (const float*)d_in[4];
  const float* wlv = (const float*)d_in[5];
  const float* wu0 = (const float*)d_in[6];
  const float* wu1 = (const float*)d_in[7];
  const float* w4  = (const float*)d_in[8];
  const float* wu2 = (const float*)d_in[9];
  const float* w5  = (const float*)d_in[10];
  const float* wu3 = (const float*)d_in[11];
  const float* w6  = (const float*)d_in[12];
  float* out = (float*)d_out;
  float* A  = (float*)d_ws;          // 4,096,000 floats arena
  float* Bb = A + 4096000;           // 16,384,000 floats arena
  // total ws use: 20,480,000 floats = 81.92 MB

  k_enc1 <<<2000, 256, 0, stream>>>(x,  w1,  A);   // p1 [32,8,250,64]
  k_enc2 <<< 400, 256, 0, stream>>>(A,  w2,  Bb);  // p2 [32,16,50,32]
  k_conv3<<< 400, 256, 0, stream>>>(Bb, w3,  A);   // h3 [32,32,50,32]
  k_pool3<<< 640, 256, 0, stream>>>(A,  Bb);       // p3 [32,32,10,16]
  k_latent<<< 15, 256, 0, stream>>>(Bb, wmu, wlv, out); // mu/lv/z -> d_out
  k_dec0 <<< 640, 256, 0, stream>>>(out, wu0, A);  // d0 [32,32,10,16]
  k_dec1 <<<6400, 256, 0, stream>>>(A,  wu1, Bb);  // d1 [32,32,50,32]
  k_c4   <<< 400, 256, 0, stream>>>(Bb, w4,  A);   // d2 [32,16,50,32]
  k_u2   <<<32000,256, 0, stream>>>(A,  wu2, Bb);  // d3 [32,16,250,64]
  k_c5   <<<2000, 256, 0, stream>>>(Bb, w5,  A);   // d4 [32,8,250,64]
  k_u3   <<<64000,256, 0, stream>>>(A,  wu3, Bb);  // d5 [32,8,500,128]
  k_c6   <<<2000, 256, 0, stream>>>(Bb, w6,  out); // d  [32,6,500,128]
}

// Round 3
// 414.360 us; speedup vs baseline: 3.7294x; 3.7294x over previous
//
#include <hip/hip_runtime.h>
#include <stdint.h>

#define DI __device__ __forceinline__

DI float lrelu(float x){ return x >= 0.0f ? x : 0.01f*x; }

// ---------------- threefry2x32, JAX key(42) => (0, 42) ----------------
DI uint32_t rotl32(uint32_t x, int d){ return (x << d) | (x >> (32 - d)); }

DI void threefry_0_42(uint32_t& x0, uint32_t& x1){
  const uint32_t ks0 = 0u, ks1 = 42u, ks2 = 0x1BD11BF0u; // 0 ^ 42 ^ 0x1BD11BDA
  x0 += ks0; x1 += ks1;
  #define TFR(d) { x0 += x1; x1 = rotl32(x1,(d)); x1 ^= x0; }
  TFR(13) TFR(15) TFR(26) TFR(6)  x0 += ks1; x1 += ks2 + 1u;
  TFR(17) TFR(29) TFR(16) TFR(24) x0 += ks2; x1 += ks0 + 2u;
  TFR(13) TFR(15) TFR(26) TFR(6)  x0 += ks0; x1 += ks1 + 3u;
  TFR(17) TFR(29) TFR(16) TFR(24) x0 += ks1; x1 += ks2 + 4u;
  TFR(13) TFR(15) TFR(26) TFR(6)  x0 += ks2; x1 += ks0 + 5u;
  #undef TFR
}

// XLA/Giles single-precision erfinv (same coefficients as chlo erf_inv f32)
DI float erfinv_f32(float x){
  float w = -log1pf(-x*x);
  float p;
  if (w < 5.0f){
    w = w - 2.5f;
    p = 2.81022636e-08f;
    p = fmaf(p, w, 3.43273939e-07f);
    p = fmaf(p, w, -3.5233877e-06f);
    p = fmaf(p, w, -4.39150654e-06f);
    p = fmaf(p, w, 0.00021858087f);
    p = fmaf(p, w, -0.00125372503f);
    p = fmaf(p, w, -0.00417768164f);
    p = fmaf(p, w, 0.246640727f);
    p = fmaf(p, w, 1.50140941f);
  } else {
    w = sqrtf(w) - 3.0f;
    p = -0.000200214257f;
    p = fmaf(p, w, 0.000100950558f);
    p = fmaf(p, w, 0.00134934322f);
    p = fmaf(p, w, -0.00367342844f);
    p = fmaf(p, w, 0.00573950773f);
    p = fmaf(p, w, -0.0076224613f);
    p = fmaf(p, w, 0.00943887047f);
    p = fmaf(p, w, 1.00167406f);
    p = fmaf(p, w, 2.83297682f);
  }
  return p * x;
}

// out offsets (floats)
#define OUT_D_OFF   0
#define OUT_MU_OFF  12288000
#define OUT_LV_OFF  (12288000 + 3840)
#define OUT_Z_OFF   (12288000 + 7680)

// =====================================================================
// enc1: conv(x,w1,SAME 3x3, 6->8) + lrelu + maxpool 2x2  -> p1[32,8,250,64]
__global__ __launch_bounds__(256) void k_enc1(const float* __restrict__ x,
                                              const float* __restrict__ w1,
                                              float* __restrict__ p1){
  __shared__ float wl[432];
  int tid = threadIdx.x;
  for (int i = tid; i < 432; i += 256) wl[i] = w1[i];
  __syncthreads();
  int t = blockIdx.x*256 + tid;
  int pw = t & 63; int u = t >> 6; int ph = u % 250; int b = u / 250;
  float acc[2][2][8];
  #pragma unroll
  for (int a=0;a<2;a++)
    #pragma unroll
    for (int d=0;d<2;d++)
      #pragma unroll
      for (int o=0;o<8;o++) acc[a][d][o] = 0.0f;
  int r0 = 2*ph - 1, c0 = 2*pw - 1;
  #pragma unroll 2
  for (int c = 0; c < 6; ++c){
    float win[4][4];
    #pragma unroll
    for (int i=0;i<4;i++){
      int r = r0 + i; bool rok = ((unsigned)r < 500u);
      #pragma unroll
      for (int j=0;j<4;j++){
        int cc = c0 + j;
        win[i][j] = (rok && (unsigned)cc < 128u) ? x[((b*6+c)*500+r)*128+cc] : 0.0f;
      }
    }
    #pragma unroll
    for (int kh=0;kh<3;kh++)
      #pragma unroll
      for (int kw=0;kw<3;kw++){
        float wv[8];
        #pragma unroll
        for (int o=0;o<8;o++) wv[o] = wl[((o*6+c)*3+kh)*3+kw];
        #pragma unroll
        for (int dy=0;dy<2;dy++)
          #pragma unroll
          for (int dx=0;dx<2;dx++){
            float v = win[dy+kh][dx+kw];
            #pragma unroll
            for (int o=0;o<8;o++) acc[dy][dx][o] = fmaf(v, wv[o], acc[dy][dx][o]);
          }
      }
  }
  #pragma unroll
  for (int o=0;o<8;o++){
    float m = fmaxf(fmaxf(acc[0][0][o], acc[0][1][o]), fmaxf(acc[1][0][o], acc[1][1][o]));
    p1[((b*8+o)*250+ph)*64+pw] = lrelu(m); // lrelu monotonic => pool-then-lrelu
  }
}

// =====================================================================
// enc2: conv(p1,w2,SAME 3x3, 8->16)+lrelu+maxpool(5,2) -> p2[32,16,50,32]
__global__ __launch_bounds__(256) void k_enc2(const float* __restrict__ in,
                                              const float* __restrict__ w2,
                                              float* __restrict__ p2){
  __shared__ float wl[1152];
  int tid = threadIdx.x;
  for (int i = tid; i < 1152; i += 256) wl[i] = w2[i];
  __syncthreads();
  int t = blockIdx.x*256 + tid;
  int dx = t & 1; int u = t >> 1;
  int pw = u & 31; u >>= 5; int ph = u % 50; int b = u / 50;
  int cw = 2*pw + dx;
  float acc[5][16];
  #pragma unroll
  for (int dy=0;dy<5;dy++)
    #pragma unroll
    for (int o=0;o<16;o++) acc[dy][o] = 0.0f;
  int r0 = 5*ph - 1, c0 = cw - 1;
  #pragma unroll 2
  for (int c = 0; c < 8; ++c){
    float win[7][3];
    #pragma unroll
    for (int i=0;i<7;i++){
      int r = r0 + i; bool rok = ((unsigned)r < 250u);
      #pragma unroll
      for (int j=0;j<3;j++){
        int cc = c0 + j;
        win[i][j] = (rok && (unsigned)cc < 64u) ? in[((b*8+c)*250+r)*64+cc] : 0.0f;
      }
    }
    #pragma unroll
    for (int kh=0;kh<3;kh++)
      #pragma unroll
      for (int kw=0;kw<3;kw++){
        float wv[16];
        #pragma unroll
        for (int o=0;o<16;o++) wv[o] = wl[((o*8+c)*3+kh)*3+kw];
        #pragma unroll
        for (int dy=0;dy<5;dy++){
          float v = win[dy+kh][kw];
          #pragma unroll
          for (int o=0;o<16;o++) acc[dy][o] = fmaf(v, wv[o], acc[dy][o]);
        }
      }
  }
  #pragma unroll
  for (int o=0;o<16;o++){
    float m = acc[0][o];
    #pragma unroll
    for (int dy=1;dy<5;dy++) m = fmaxf(m, acc[dy][o]);
    m = fmaxf(m, __shfl_xor(m, 1));
    if (dx == 0) p2[((b*16+o)*50+ph)*32+pw] = lrelu(m);
  }
}

// =====================================================================
// conv3: conv(p2,w3,SAME 3x3, 16->32)+lrelu -> h3[32,32,50,32]
__global__ __launch_bounds__(256) void k_conv3(const float* __restrict__ in,
                                               const float* __restrict__ w3,
                                               float* __restrict__ outp){
  __shared__ float wl[4608];
  int tid = threadIdx.x;
  for (int i = tid; i < 4608; i += 256) wl[i] = w3[i];
  __syncthreads();
  int t = blockIdx.x*256 + tid;
  int w = t & 31; int u = t >> 5; int h = u % 50; u /= 50; int oh = u & 1; int b = u >> 1;
  float acc[16];
  #pragma unroll
  for (int o=0;o<16;o++) acc[o] = 0.0f;
  int r0 = h - 1, c0 = w - 1;
  #pragma unroll 2
  for (int c = 0; c < 16; ++c){
    float win[3][3];
    #pragma unroll
    for (int i=0;i<3;i++){
      int r = r0 + i; bool rok = ((unsigned)r < 50u);
      #pragma unroll
      for (int j=0;j<3;j++){
        int cc = c0 + j;
        win[i][j] = (rok && (unsigned)cc < 32u) ? in[((b*16+c)*50+r)*32+cc] : 0.0f;
      }
    }
    #pragma unroll
    for (int kh=0;kh<3;kh++)
      #pragma unroll
      for (int kw=0;kw<3;kw++){
        float v = win[kh][kw];
        #pragma unroll
        for (int o=0;o<16;o++)
          acc[o] = fmaf(v, wl[(((oh*16+o)*16+c)*3+kh)*3+kw], acc[o]);
      }
  }
  #pragma unroll
  for (int o=0;o<16;o++)
    outp[((b*32 + oh*16 + o)*50 + h)*32 + w] = lrelu(acc[o]);
}

// =====================================================================
// pool3: maxpool(5,2) on h3 -> p3[32,32,10,16]
__global__ __launch_bounds__(256) void k_pool3(const float* __restrict__ in,
                                               float* __restrict__ outp){
  int t = blockIdx.x*256 + threadIdx.x;
  int pw = t & 15; int u = t >> 4; int ph = u % 10; u /= 10; int o = u & 31; int b = u >> 5;
  float m = -INFINITY;
  #pragma unroll
  for (int dh=0;dh<5;dh++)
    #pragma unroll
    for (int dw=0;dw<2;dw++)
      m = fmaxf(m, in[((b*32+o)*50 + 5*ph+dh)*32 + 2*pw+dw]);
  outp[((b*32+o)*10+ph)*16+pw] = m;
}

// =====================================================================
// latent: mu/logvar conv (1,5) VALID 32->1, reparameterize with threefry eps
// eps uses JAX *partitionable* threefry: per element t,
//   (y0,y1) = threefry(key=(0,42), counter=(0,t)); bits = y0 ^ y1.
__global__ __launch_bounds__(256) void k_latent(const float* __restrict__ p3,
                                                const float* __restrict__ wmu,
                                                const float* __restrict__ wlv,
                                                float* __restrict__ outp){
  int t = blockIdx.x*256 + threadIdx.x; // 3840 total
  int w = t % 12; int h = (t/12) % 10; int b = t/120;
  float mu = 0.0f, lv = 0.0f;
  for (int c = 0; c < 32; ++c){
    const float* row = p3 + ((b*32+c)*10+h)*16 + w;
    #pragma unroll
    for (int kw=0;kw<5;kw++){
      float v = row[kw];
      mu = fmaf(v, wmu[c*5+kw], mu);
      lv = fmaf(v, wlv[c*5+kw], lv);
    }
  }
  uint32_t x0 = 0u, x1 = (uint32_t)t;
  threefry_0_42(x0, x1);
  uint32_t bits = x0 ^ x1;
  float f = __uint_as_float((bits >> 9) | 0x3f800000u) - 1.0f; // [0,1)
  const float lo = -0.99999994f; // nextafter(-1,0) in f32; (1-lo) rounds to 2.0f
  float uu = fmaxf(lo, f * 2.0f + lo);
  float eps = 1.41421356f * erfinv_f32(uu);
  float z = mu + eps * expf(0.5f * lv);
  outp[OUT_MU_OFF + t] = mu;
  outp[OUT_LV_OFF + t] = lv;
  outp[OUT_Z_OFF  + t] = z;
}

// =====================================================================
// dec0: convT(z, wu0[32,1,1,5], stride 1, VALID) + lrelu -> d0[32,32,10,16]
__global__ __launch_bounds__(256) void k_dec0(const float* __restrict__ outp, // d_out base (z lives there)
                                              const float* __restrict__ wu0,
                                              float* __restrict__ d0){
  int t = blockIdx.x*256 + threadIdx.x;
  int w = t & 15; int u = t >> 4; int h = u % 10; u /= 10; int o = u & 31; int b = u >> 5;
  const float* z = outp + OUT_Z_OFF;
  float a = 0.0f;
  #pragma unroll
  for (int kw=0;kw<5;kw++){
    int ww = w + kw - 4;
    if ((unsigned)ww < 12u) a = fmaf(z[b*120 + h*12 + ww], wu0[o*5+kw], a);
  }
  d0[((b*32+o)*10+h)*16+w] = lrelu(a);
}

// =====================================================================
// dec1: convT(d0, wu1[32,32,5,2], strides (5,2)) + lrelu -> d1[32,32,50,32]
// kernel==stride: out[o,5i+r,2j+s] = sum_c d0[c,i,j]*wu1[o,c,4-r,1-s]
__global__ __launch_bounds__(256) void k_dec1(const float* __restrict__ d0,
                                              const float* __restrict__ wu1,
                                              float* __restrict__ d1){
  int t = blockIdx.x*256 + threadIdx.x;
  int wo = t & 31; int u = t >> 5; int ho = u % 50; u /= 50; int o = u & 31; int b = u >> 5;
  int i = ho / 5, r = ho - 5*i, jj = wo >> 1, s = wo & 1;
  const float* ip = d0 + b*5120 + i*16 + jj;             // + c*160
  const float* wp = wu1 + (o*32*5 + (4-r))*2 + (1-s);    // + c*10
  float a = 0.0f;
  #pragma unroll 8
  for (int c=0;c<32;c++) a = fmaf(ip[c*160], wp[c*10], a);
  d1[((b*32+o)*50+ho)*32+wo] = lrelu(a);
}

// =====================================================================
// c4: conv(d1, w4[16,32,3,3], SAME)+lrelu -> d2[32,16,50,32]
__global__ __launch_bounds__(256) void k_c4(const float* __restrict__ in,
                                            const float* __restrict__ w4,
                                            float* __restrict__ outp){
  __shared__ float wl[4608];
  int tid = threadIdx.x;
  for (int i = tid; i < 4608; i += 256) wl[i] = w4[i];
  __syncthreads();
  int t = blockIdx.x*256 + tid;
  int w = t & 31; int u = t >> 5; int h = u % 50; u /= 50; int oh = u & 1; int b = u >> 1;
  float acc[8];
  #pragma unroll
  for (int o=0;o<8;o++) acc[o] = 0.0f;
  int r0 = h - 1, c0 = w - 1;
  #pragma unroll 2
  for (int c = 0; c < 32; ++c){
    float win[3][3];
    #pragma unroll
    for (int i=0;i<3;i++){
      int r = r0 + i; bool rok = ((unsigned)r < 50u);
      #pragma unroll
      for (int j=0;j<3;j++){
        int cc = c0 + j;
        win[i][j] = (rok && (unsigned)cc < 32u) ? in[((b*32+c)*50+r)*32+cc] : 0.0f;
      }
    }
    #pragma unroll
    for (int kh=0;kh<3;kh++)
      #pragma unroll
      for (int kw=0;kw<3;kw++){
        float v = win[kh][kw];
        #pragma unroll
        for (int o=0;o<8;o++)
          acc[o] = fmaf(v, wl[(((oh*8+o)*32+c)*3+kh)*3+kw], acc[o]);
      }
  }
  #pragma unroll
  for (int o=0;o<8;o++)
    outp[((b*16 + oh*8 + o)*50 + h)*32 + w] = lrelu(acc[o]);
}

// =====================================================================
// u2: convT(d2, wu2[16,16,5,2], strides (5,2)) + lrelu -> d3[32,16,250,64]
__global__ __launch_bounds__(256) void k_u2(const float* __restrict__ d2,
                                            const float* __restrict__ wu2,
                                            float* __restrict__ d3){
  int t = blockIdx.x*256 + threadIdx.x;
  int w = t & 63; int u = t >> 6; int h = u % 250; u /= 250; int o = u & 15; int b = u >> 4;
  int i = h / 5, r = h - 5*i, jj = w >> 1, s = w & 1;
  const float* ip = d2 + b*25600 + i*32 + jj;            // + c*1600
  const float* wp = wu2 + (o*16*5 + (4-r))*2 + (1-s);    // + c*10
  float a = 0.0f;
  #pragma unroll 8
  for (int c=0;c<16;c++) a = fmaf(ip[c*1600], wp[c*10], a);
  d3[((b*16+o)*250+h)*64+w] = lrelu(a);
}

// =====================================================================
// c5: conv(d3, w5[8,16,3,3], SAME)+lrelu -> d4[32,8,250,64]
__global__ __launch_bounds__(256) void k_c5(const float* __restrict__ in,
                                            const float* __restrict__ w5,
                                            float* __restrict__ outp){
  __shared__ float wl[1152];
  int tid = threadIdx.x;
  for (int i = tid; i < 1152; i += 256) wl[i] = w5[i];
  __syncthreads();
  int t = blockIdx.x*256 + tid;
  int w = t & 63; int u = t >> 6; int h = u % 250; int b = u / 250;
  float acc[8];
  #pragma unroll
  for (int o=0;o<8;o++) acc[o] = 0.0f;
  int r0 = h - 1, c0 = w - 1;
  #pragma unroll 2
  for (int c = 0; c < 16; ++c){
    float win[3][3];
    #pragma unroll
    for (int i=0;i<3;i++){
      int r = r0 + i; bool rok = ((unsigned)r < 250u);
      #pragma unroll
      for (int j=0;j<3;j++){
        int cc = c0 + j;
        win[i][j] = (rok && (unsigned)cc < 64u) ? in[((b*16+c)*250+r)*64+cc] : 0.0f;
      }
    }
    #pragma unroll
    for (int kh=0;kh<3;kh++)
      #pragma unroll
      for (int kw=0;kw<3;kw++){
        float v = win[kh][kw];
        #pragma unroll
        for (int o=0;o<8;o++)
          acc[o] = fmaf(v, wl[((o*16+c)*3+kh)*3+kw], acc[o]);
      }
  }
  #pragma unroll
  for (int o=0;o<8;o++)
    outp[((b*8+o)*250+h)*64+w] = lrelu(acc[o]);
}

// =====================================================================
// u3: convT(d4, wu3[8,8,2,2], strides (2,2)) + lrelu -> d5[32,8,500,128]
__global__ __launch_bounds__(256) void k_u3(const float* __restrict__ d4,
                                            const float* __restrict__ wu3,
                                            float* __restrict__ d5){
  int t = blockIdx.x*256 + threadIdx.x;
  int w = t & 127; int u = t >> 7; int h = u % 500; u /= 500; int o = u & 7; int b = u >> 3;
  int i = h >> 1, r = h & 1, jj = w >> 1, s = w & 1;
  const float* ip = d4 + b*128000 + i*64 + jj;           // + c*16000
  const float* wp = wu3 + (o*8*2 + (1-r))*2 + (1-s);     // + c*4
  float a = 0.0f;
  #pragma unroll
  for (int c=0;c<8;c++) a = fmaf(ip[c*16000], wp[c*4], a);
  d5[((b*8+o)*500+h)*128+w] = lrelu(a);
}

// =====================================================================
// c6: conv(d5, w6[6,8,3,3], SAME)+lrelu -> d_out[32,6,500,128]
__global__ __launch_bounds__(256) void k_c6(const float* __restrict__ in,
                                            const float* __restrict__ w6,
                                            float* __restrict__ outp){
  __shared__ float wl[432];
  int tid = threadIdx.x;
  for (int i = tid; i < 432; i += 256) wl[i] = w6[i];
  __syncthreads();
  int t = blockIdx.x*256 + tid;
  int w = t & 127; int u = t >> 7; int h = u % 500; int b = u / 500;
  float acc[6];
  #pragma unroll
  for (int o=0;o<6;o++) acc[o] = 0.0f;
  int r0 = h - 1, c0 = w - 1;
  #pragma unroll 2
  for (int c = 0; c < 8; ++c){
    float win[3][3];
    #pragma unroll
    for (int i=0;i<3;i++){
      int r = r0 + i; bool rok = ((unsigned)r < 500u);
      #pragma unroll
      for (int j=0;j<3;j++){
        int cc = c0 + j;
        win[i][j] = (rok && (unsigned)cc < 128u) ? in[((b*8+c)*500+r)*128+cc] : 0.0f;
      }
    }
    #pragma unroll
    for (int kh=0;kh<3;kh++)
      #pragma unroll
      for (int kw=0;kw<3;kw++){
        float v = win[kh][kw];
        #pragma unroll
        for (int o=0;o<6;o++)
          acc[o] = fmaf(v, wl[((o*8+c)*3+kh)*3+kw], acc[o]);
      }
  }
  #pragma unroll
  for (int o=0;o<6;o++)
    outp[((b*6+o)*500+h)*128+w] = lrelu(acc[o]);
}

// =====================================================================
extern "C" void kernel_launch(void* const* d_in, const int* in_sizes, int n_in,
                              void* d_out, int out_size, void* d_ws, size_t ws_size,
                              hipStream_t stream){
  const float* x   = (const float*)d_in[0];
  const float* w1  = (const float*)d_in[1];
  const float* w2  = (const float*)d_in[2];
  const float* w3  = (const float*)d_in[3];
  const float* wmu = (const float*)d_in[4];
  const float* wlv = (const float*)d_in[5];
  const float* wu0 = (const float*)d_in[6];
  const float* wu1 = (const float*)d_in[7];
  const float* w4  = (const float*)d_in[8];
  const float* wu2 = (const float*)d_in[9];
  const float* w5  = (const float*)d_in[10];
  const float* wu3 = (const float*)d_in[11];
  const float* w6  = (const float*)d_in[12];
  float* out = (float*)d_out;
  float* A  = (float*)d_ws;          // 4,096,000 floats arena
  float* Bb = A + 4096000;           // 16,384,000 floats arena
  // total ws use: 20,480,000 floats = 81.92 MB

  k_enc1 <<<2000, 256, 0, stream>>>(x,  w1,  A);   // p1 [32,8,250,64]
  k_enc2 <<< 400, 256, 0, stream>>>(A,  w2,  Bb);  // p2 [32,16,50,32]
  k_conv3<<< 400, 256, 0, stream>>>(Bb, w3,  A);   // h3 [32,32,50,32]
  k_pool3<<< 640, 256, 0, stream>>>(A,  Bb);       // p3 [32,32,10,16]
  k_latent<<< 15, 256, 0, stream>>>(Bb, wmu, wlv, out); // mu/lv/z -> d_out
  k_dec0 <<< 640, 256, 0, stream>>>(out, wu0, A);  // d0 [32,32,10,16]
  k_dec1 <<<6400, 256, 0, stream>>>(A,  wu1, Bb);  // d1 [32,32,50,32]
  k_c4   <<< 400, 256, 0, stream>>>(Bb, w4,  A);   // d2 [32,16,50,32]
  k_u2   <<<32000,256, 0, stream>>>(A,  wu2, Bb);  // d3 [32,16,250,64]
  k_c5   <<<2000, 256, 0, stream>>>(Bb, w5,  A);   // d4 [32,8,250,64]
  k_u3   <<<64000,256, 0, stream>>>(A,  wu3, Bb);  // d5 [32,8,500,128]
  k_c6   <<<2000, 256, 0, stream>>>(Bb, w6,  out); // d  [32,6,500,128]
}